// Round 1
// baseline (2296.337 us; speedup 1.0000x reference)
//
#include <hip/hip_runtime.h>
#include <math.h>

#define T_  1024
#define D_  2048
#define H_  32
#define KV_ 8
#define HD_ 64
#define E_  8
#define I_  1024
#define SI_ 4096

constexpr float ATTN_MULT = 0.0078125f;
constexpr float RES_MULT  = 0.22f;
constexpr float EPS_      = 1e-6f;
constexpr size_t TD = (size_t)T_ * D_;

// ---------------------------------------------------------------- RMSNorm
__global__ __launch_bounds__(256) void rmsnorm_k(const float* __restrict__ x,
                                                 const float* __restrict__ w,
                                                 float* __restrict__ o) {
  int t = blockIdx.x;
  const float* xr = x + (size_t)t * D_;
  float ss = 0.f;
  for (int d = threadIdx.x * 4; d < D_; d += 1024) {
    float4 v = *(const float4*)(xr + d);
    ss += v.x * v.x + v.y * v.y + v.z * v.z + v.w * v.w;
  }
  int lane = threadIdx.x & 63, wid = threadIdx.x >> 6;
  #pragma unroll
  for (int off = 32; off >= 1; off >>= 1) ss += __shfl_xor(ss, off);
  __shared__ float red[4];
  if (lane == 0) red[wid] = ss;
  __syncthreads();
  float tot = red[0] + red[1] + red[2] + red[3];
  float rs = rsqrtf(tot / (float)D_ + EPS_);
  float* orow = o + (size_t)t * D_;
  for (int d = threadIdx.x * 4; d < D_; d += 1024) {
    float4 v = *(const float4*)(xr + d);
    float4 ww = *(const float4*)(w + d);
    float4 r;
    r.x = v.x * rs * ww.x; r.y = v.y * rs * ww.y;
    r.z = v.z * rs * ww.z; r.w = v.w * rs * ww.w;
    *(float4*)(orow + d) = r;
  }
}

// ---------------------------------------------------------------- generic 64x128 SGEMM body
// A: MxK (lda=K), B: KxN (ldb=N), C: MxN (ldc=N). block = 256 threads, tile 64x128.
template<bool RES>
__device__ __forceinline__ void gemm_body(const float* __restrict__ A,
                                          const float* __restrict__ B,
                                          float* __restrict__ C,
                                          const float* __restrict__ resid,
                                          float alpha, int m0, int n0, int K, int N) {
  __shared__ float AsT[16][68];
  __shared__ float Bs[16][128];
  int tid = threadIdx.x, tx = tid & 15, ty = tid >> 4;
  float c[4][8] = {};
  int arow = tid >> 2, akq = tid & 3;
  const float* Ap = A + (size_t)(m0 + arow) * K + akq * 4;
  int bk = tid >> 4, bn = (tid & 15) * 8;
  const float* Bp0 = B + (size_t)bk * N + n0 + bn;
  for (int kt = 0; kt < K; kt += 16) {
    float4 av = *(const float4*)(Ap + kt);
    const float* Bp = Bp0 + (size_t)kt * N;
    float4 b0 = *(const float4*)(Bp);
    float4 b1 = *(const float4*)(Bp + 4);
    __syncthreads();
    AsT[akq * 4 + 0][arow] = av.x; AsT[akq * 4 + 1][arow] = av.y;
    AsT[akq * 4 + 2][arow] = av.z; AsT[akq * 4 + 3][arow] = av.w;
    *(float4*)&Bs[bk][bn]     = b0;
    *(float4*)&Bs[bk][bn + 4] = b1;
    __syncthreads();
    #pragma unroll
    for (int k = 0; k < 16; k++) {
      float4 a  = *(const float4*)&AsT[k][ty * 4];
      float4 p  = *(const float4*)&Bs[k][tx * 4];
      float4 qq = *(const float4*)&Bs[k][64 + tx * 4];
      float aa[4] = {a.x, a.y, a.z, a.w};
      float bb[8] = {p.x, p.y, p.z, p.w, qq.x, qq.y, qq.z, qq.w};
      #pragma unroll
      for (int mi = 0; mi < 4; mi++)
        #pragma unroll
        for (int j = 0; j < 8; j++) c[mi][j] += aa[mi] * bb[j];
    }
  }
  #pragma unroll
  for (int mi = 0; mi < 4; mi++) {
    int row = m0 + ty * 4 + mi;
    float* Cp = C + (size_t)row * N + n0;
    const float* Rp = RES ? (resid + (size_t)row * N + n0) : nullptr;
    #pragma unroll
    for (int j = 0; j < 4; j++) {
      float v0 = alpha * c[mi][j];
      float v1 = alpha * c[mi][4 + j];
      if (RES) { v0 += Rp[tx * 4 + j]; v1 += Rp[64 + tx * 4 + j]; }
      Cp[tx * 4 + j]      = v0;
      Cp[64 + tx * 4 + j] = v1;
    }
  }
}

template<bool RES>
__global__ __launch_bounds__(256) void sgemm_dense_k(const float* __restrict__ A,
                                                     const float* __restrict__ B,
                                                     float* __restrict__ C,
                                                     const float* __restrict__ resid,
                                                     float alpha, int K, int N) {
  gemm_body<RES>(A, B, C, resid, alpha, blockIdx.y * 64, blockIdx.x * 128, K, N);
}

// fused QKV: grid.x 0..23 -> wq cols (16 tiles), wk (4), wv (4)
__global__ __launch_bounds__(256) void sgemm_qkv_k(const float* __restrict__ A,
                                                   const float* __restrict__ wq,
                                                   const float* __restrict__ wk,
                                                   const float* __restrict__ wv,
                                                   float* __restrict__ qo,
                                                   float* __restrict__ ko,
                                                   float* __restrict__ vo) {
  int nt = blockIdx.x;
  const float* B; float* C; int N, n0;
  if (nt < 16)      { B = wq; C = qo; N = 2048; n0 = nt * 128; }
  else if (nt < 20) { B = wk; C = ko; N = 512;  n0 = (nt - 16) * 128; }
  else              { B = wv; C = vo; N = 512;  n0 = (nt - 20) * 128; }
  gemm_body<false>(A, B, C, nullptr, 1.f, blockIdx.y * 64, n0, D_, N);
}

// ---------------------------------------------------------------- RoPE (in place)
__global__ __launch_bounds__(256) void rope_k(float* __restrict__ x,
                                              const int* __restrict__ pos, int nheads) {
  int id = blockIdx.x * 256 + threadIdx.x;
  int total = T_ * nheads * 32;
  if (id >= total) return;
  int j = id & 31;
  int th = id >> 5;
  int hh = th % nheads;
  int t = th / nheads;
  float inv = powf(10000.0f, -(float)(2 * j) / (float)HD_);
  float ang = (float)pos[t] * inv;
  float sn, cs;
  sincosf(ang, &sn, &cs);
  size_t base = ((size_t)t * nheads + hh) * HD_;
  float x1 = x[base + j], x2 = x[base + j + 32];
  x[base + j]      = x1 * cs - x2 * sn;
  x[base + j + 32] = x2 * cs + x1 * sn;
}

// ---------------------------------------------------------------- flash attention fp32
// block: (head h, 64 q rows). 256 threads: tx=s/d quad, ty=i quad.
__global__ __launch_bounds__(256) void attn_k(const float* __restrict__ q,
                                              const float* __restrict__ kb,
                                              const float* __restrict__ vb,
                                              float* __restrict__ o) {
  int h = blockIdx.x, qt = blockIdx.y;
  __shared__ float qsT[64][68];
  __shared__ float ksT[64][68];
  __shared__ float vs[64][68];
  __shared__ float psT[64][68];
  int tid = threadIdx.x, tx = tid & 15, ty = tid >> 4;
  {
    int i = tid >> 2, dq = (tid & 3) * 16;
    const float* qp = q + (size_t)(qt * 64 + i) * (H_ * HD_) + h * HD_ + dq;
    #pragma unroll
    for (int jj = 0; jj < 16; jj += 4) {
      float4 v4 = *(const float4*)(qp + jj);
      qsT[dq + jj + 0][i] = v4.x * ATTN_MULT;
      qsT[dq + jj + 1][i] = v4.y * ATTN_MULT;
      qsT[dq + jj + 2][i] = v4.z * ATTN_MULT;
      qsT[dq + jj + 3][i] = v4.w * ATTN_MULT;
    }
  }
  float m_i[4], l_i[4], o_acc[4][4];
  #pragma unroll
  for (int ii = 0; ii < 4; ii++) {
    m_i[ii] = -1e30f; l_i[ii] = 0.f;
    #pragma unroll
    for (int dj = 0; dj < 4; dj++) o_acc[ii][dj] = 0.f;
  }
  int kvh = h >> 2;
  for (int st = 0; st <= qt; st++) {
    __syncthreads();
    {
      int s = tid >> 2, dq = (tid & 3) * 16;
      const float* kp = kb + (size_t)(st * 64 + s) * (KV_ * HD_) + kvh * HD_ + dq;
      const float* vp = vb + (size_t)(st * 64 + s) * (KV_ * HD_) + kvh * HD_ + dq;
      #pragma unroll
      for (int jj = 0; jj < 16; jj += 4) {
        float4 v4 = *(const float4*)(kp + jj);
        ksT[dq + jj + 0][s] = v4.x; ksT[dq + jj + 1][s] = v4.y;
        ksT[dq + jj + 2][s] = v4.z; ksT[dq + jj + 3][s] = v4.w;
        float4 w4 = *(const float4*)(vp + jj);
        *(float4*)&vs[s][dq + jj] = w4;
      }
    }
    __syncthreads();
    float sc[4][4] = {};
    #pragma unroll 8
    for (int d = 0; d < 64; d++) {
      float4 a = *(const float4*)&qsT[d][ty * 4];
      float4 b = *(const float4*)&ksT[d][tx * 4];
      float aa[4] = {a.x, a.y, a.z, a.w};
      float bb[4] = {b.x, b.y, b.z, b.w};
      #pragma unroll
      for (int ii = 0; ii < 4; ii++)
        #pragma unroll
        for (int sj = 0; sj < 4; sj++) sc[ii][sj] += aa[ii] * bb[sj];
    }
    if (st == qt) {
      #pragma unroll
      for (int ii = 0; ii < 4; ii++)
        #pragma unroll
        for (int sj = 0; sj < 4; sj++)
          if (tx * 4 + sj > ty * 4 + ii) sc[ii][sj] = -1e30f;
    }
    float p[4][4];
    #pragma unroll
    for (int ii = 0; ii < 4; ii++) {
      float mt = fmaxf(fmaxf(sc[ii][0], sc[ii][1]), fmaxf(sc[ii][2], sc[ii][3]));
      #pragma unroll
      for (int off = 8; off >= 1; off >>= 1) mt = fmaxf(mt, __shfl_xor(mt, off));
      float mn = fmaxf(m_i[ii], mt);
      float corr = expf(m_i[ii] - mn);
      float ssum = 0.f;
      #pragma unroll
      for (int sj = 0; sj < 4; sj++) {
        float pv = expf(sc[ii][sj] - mn);
        p[ii][sj] = pv; ssum += pv;
      }
      #pragma unroll
      for (int off = 8; off >= 1; off >>= 1) ssum += __shfl_xor(ssum, off);
      l_i[ii] = l_i[ii] * corr + ssum;
      m_i[ii] = mn;
      #pragma unroll
      for (int dj = 0; dj < 4; dj++) o_acc[ii][dj] *= corr;
    }
    #pragma unroll
    for (int sj = 0; sj < 4; sj++) {
      float4 w4 = make_float4(p[0][sj], p[1][sj], p[2][sj], p[3][sj]);
      *(float4*)&psT[tx * 4 + sj][ty * 4] = w4;
    }
    __syncthreads();
    #pragma unroll 8
    for (int s = 0; s < 64; s++) {
      float4 p4 = *(const float4*)&psT[s][ty * 4];
      float4 v4 = *(const float4*)&vs[s][tx * 4];
      float pp[4] = {p4.x, p4.y, p4.z, p4.w};
      float vv[4] = {v4.x, v4.y, v4.z, v4.w};
      #pragma unroll
      for (int ii = 0; ii < 4; ii++)
        #pragma unroll
        for (int dj = 0; dj < 4; dj++) o_acc[ii][dj] += pp[ii] * vv[dj];
    }
  }
  #pragma unroll
  for (int ii = 0; ii < 4; ii++) {
    float invl = 1.f / l_i[ii];
    int row = qt * 64 + ty * 4 + ii;
    float* op = o + (size_t)row * (H_ * HD_) + h * HD_ + tx * 4;
    #pragma unroll
    for (int dj = 0; dj < 4; dj++) op[dj] = o_acc[ii][dj] * invl;
  }
}

// ---------------------------------------------------------------- router top-2
__global__ __launch_bounds__(256) void router_k(const float* __restrict__ xn,
                                                const float* __restrict__ rw,
                                                int* __restrict__ tokE,
                                                float* __restrict__ tokW) {
  int t = blockIdx.x, tid = threadIdx.x;
  const float* xr = xn + (size_t)t * D_;
  float acc[E_] = {};
  for (int d = tid * 4; d < D_; d += 1024) {
    float4 xv = *(const float4*)(xr + d);
    #pragma unroll
    for (int e = 0; e < E_; e++) {
      float4 wv = *(const float4*)(rw + (size_t)e * D_ + d);
      acc[e] += xv.x * wv.x + xv.y * wv.y + xv.z * wv.z + xv.w * wv.w;
    }
  }
  int lane = tid & 63, wid = tid >> 6;
  #pragma unroll
  for (int e = 0; e < E_; e++)
    #pragma unroll
    for (int off = 32; off >= 1; off >>= 1) acc[e] += __shfl_xor(acc[e], off);
  __shared__ float red[E_][4];
  if (lane == 0)
    #pragma unroll
    for (int e = 0; e < E_; e++) red[e][wid] = acc[e];
  __syncthreads();
  if (tid == 0) {
    float l[E_];
    #pragma unroll
    for (int e = 0; e < E_; e++) l[e] = red[e][0] + red[e][1] + red[e][2] + red[e][3];
    int e0 = 0;
    for (int e = 1; e < E_; e++) if (l[e] > l[e0]) e0 = e;
    int e1 = (e0 == 0) ? 1 : 0;
    for (int e = 0; e < E_; e++) if (e != e0 && l[e] > l[e1]) e1 = e;
    float w0 = 1.f / (1.f + expf(l[e1] - l[e0]));
    tokE[t * 2] = e0; tokE[t * 2 + 1] = e1;
    tokW[t * 2] = w0; tokW[t * 2 + 1] = 1.f - w0;
  }
}

__global__ __launch_bounds__(256) void count_k(const int* __restrict__ tokE,
                                               int* __restrict__ cnt, int* __restrict__ off,
                                               int* __restrict__ cursor) {
  __shared__ int hc[E_];
  if (threadIdx.x < E_) hc[threadIdx.x] = 0;
  __syncthreads();
  for (int i = threadIdx.x; i < T_ * 2; i += 256) atomicAdd(&hc[tokE[i]], 1);
  __syncthreads();
  if (threadIdx.x == 0) {
    int run = 0;
    for (int e = 0; e < E_; e++) { cnt[e] = hc[e]; off[e] = run; run += hc[e]; cursor[e] = 0; }
  }
}

__global__ __launch_bounds__(256) void scatter_k(const int* __restrict__ tokE,
                                                 const float* __restrict__ tokW,
                                                 const int* __restrict__ off,
                                                 int* __restrict__ cursor,
                                                 int* __restrict__ entTok,
                                                 float* __restrict__ entW) {
  int i = blockIdx.x * 256 + threadIdx.x;
  if (i >= T_ * 2) return;
  int e = tokE[i];
  int pos = atomicAdd(&cursor[e], 1);
  entTok[off[e] + pos] = i;          // packed t*2 + slot
  entW[off[e] + pos] = tokW[i];
}

// ---------------------------------------------------------------- dual-B GEMM + SiLU
// out[m][n] = silu(A@Bg)[m][n] * (A@Bu)[m][n] * wt[m]; tile 64x64
template<bool EXPERT>
__global__ __launch_bounds__(256) void gemm_dual_silu_k(const float* __restrict__ Abase,
    const float* __restrict__ Bbase, int ldb, int upOff, long Bstride,
    float* __restrict__ Out, int ldo,
    const int* __restrict__ entTok, const float* __restrict__ entW,
    const int* __restrict__ cnt, const int* __restrict__ off, int K) {
  int count, goff;
  const float* B;
  if (EXPERT) {
    int e = blockIdx.z; count = cnt[e]; goff = off[e];
    B = Bbase + (size_t)e * Bstride;
  } else { count = T_; goff = 0; B = Bbase; }
  int m0 = blockIdx.y * 64;
  if (m0 >= count) return;
  int n0 = blockIdx.x * 64;
  __shared__ float AsT[16][68];
  __shared__ float Bg[16][64];
  __shared__ float Bu[16][64];
  int tid = threadIdx.x, tx = tid & 15, ty = tid >> 4;
  float cg[4][4] = {}, cu[4][4] = {};
  int arow = tid >> 2, akq = tid & 3;
  int am = m0 + arow; if (am >= count) am = count - 1;
  int grow = EXPERT ? (entTok[goff + am] >> 1) : am;
  const float* Ap = Abase + (size_t)grow * K + akq * 4;
  int bk = tid >> 4, bn = (tid & 15) * 4;
  for (int kt = 0; kt < K; kt += 16) {
    float4 av = *(const float4*)(Ap + kt);
    const float* Bp = B + (size_t)(kt + bk) * ldb + n0 + bn;
    float4 g4 = *(const float4*)(Bp);
    float4 u4 = *(const float4*)(Bp + upOff);
    __syncthreads();
    AsT[akq * 4 + 0][arow] = av.x; AsT[akq * 4 + 1][arow] = av.y;
    AsT[akq * 4 + 2][arow] = av.z; AsT[akq * 4 + 3][arow] = av.w;
    *(float4*)&Bg[bk][bn] = g4;
    *(float4*)&Bu[bk][bn] = u4;
    __syncthreads();
    #pragma unroll
    for (int k = 0; k < 16; k++) {
      float4 a  = *(const float4*)&AsT[k][ty * 4];
      float4 bg = *(const float4*)&Bg[k][tx * 4];
      float4 bu = *(const float4*)&Bu[k][tx * 4];
      float aa[4] = {a.x, a.y, a.z, a.w};
      float gg[4] = {bg.x, bg.y, bg.z, bg.w};
      float uu[4] = {bu.x, bu.y, bu.z, bu.w};
      #pragma unroll
      for (int mi = 0; mi < 4; mi++)
        #pragma unroll
        for (int j = 0; j < 4; j++) {
          cg[mi][j] += aa[mi] * gg[j];
          cu[mi][j] += aa[mi] * uu[j];
        }
    }
  }
  #pragma unroll
  for (int mi = 0; mi < 4; mi++) {
    int m = m0 + ty * 4 + mi;
    if (m < count) {
      float wt = EXPERT ? entW[goff + m] : 1.f;
      float* Op = Out + (size_t)(goff + m) * ldo + n0 + tx * 4;
      #pragma unroll
      for (int j = 0; j < 4; j++) {
        float g = cg[mi][j], u = cu[mi][j];
        float s = g / (1.f + expf(-g));
        Op[j] = s * u * wt;
      }
    }
  }
}

// ---------------------------------------------------------------- expert w2 with row scatter
__global__ __launch_bounds__(256) void gemm_w2_k(const float* __restrict__ act,
    const float* __restrict__ w2b, float* __restrict__ pout,
    const int* __restrict__ entTok, const int* __restrict__ cnt,
    const int* __restrict__ off) {
  int e = blockIdx.z, count = cnt[e];
  int m0 = blockIdx.y * 64;
  if (m0 >= count) return;
  int goff = off[e];
  const float* A = act + (size_t)goff * I_;
  const float* B = w2b + (size_t)e * I_ * D_;
  int n0 = blockIdx.x * 128;
  __shared__ float AsT[16][68];
  __shared__ float Bs[16][128];
  int tid = threadIdx.x, tx = tid & 15, ty = tid >> 4;
  float c[4][8] = {};
  int arow = tid >> 2, akq = tid & 3;
  int am = m0 + arow; if (am >= count) am = count - 1;
  const float* Ap = A + (size_t)am * I_ + akq * 4;
  int bk = tid >> 4, bn = (tid & 15) * 8;
  const float* Bp0 = B + (size_t)bk * D_ + n0 + bn;
  for (int kt = 0; kt < I_; kt += 16) {
    float4 av = *(const float4*)(Ap + kt);
    const float* Bp = Bp0 + (size_t)kt * D_;
    float4 b0 = *(const float4*)(Bp);
    float4 b1 = *(const float4*)(Bp + 4);
    __syncthreads();
    AsT[akq * 4 + 0][arow] = av.x; AsT[akq * 4 + 1][arow] = av.y;
    AsT[akq * 4 + 2][arow] = av.z; AsT[akq * 4 + 3][arow] = av.w;
    *(float4*)&Bs[bk][bn] = b0;
    *(float4*)&Bs[bk][bn + 4] = b1;
    __syncthreads();
    #pragma unroll
    for (int k = 0; k < 16; k++) {
      float4 a  = *(const float4*)&AsT[k][ty * 4];
      float4 p  = *(const float4*)&Bs[k][tx * 4];
      float4 qq = *(const float4*)&Bs[k][64 + tx * 4];
      float aa[4] = {a.x, a.y, a.z, a.w};
      float bb[8] = {p.x, p.y, p.z, p.w, qq.x, qq.y, qq.z, qq.w};
      #pragma unroll
      for (int mi = 0; mi < 4; mi++)
        #pragma unroll
        for (int j = 0; j < 8; j++) c[mi][j] += aa[mi] * bb[j];
    }
  }
  #pragma unroll
  for (int mi = 0; mi < 4; mi++) {
    int m = m0 + ty * 4 + mi;
    if (m < count) {
      int prow = entTok[goff + m];
      float* Cp = pout + (size_t)prow * D_ + n0;
      #pragma unroll
      for (int j = 0; j < 4; j++) {
        Cp[tx * 4 + j]      = c[mi][j];
        Cp[64 + tx * 4 + j] = c[mi][4 + j];
      }
    }
  }
}

// ---------------------------------------------------------------- combine
__global__ __launch_bounds__(256) void combine_k(const float* __restrict__ h1,
                                                 const float* __restrict__ pout,
                                                 const float* __restrict__ sho,
                                                 float* __restrict__ out0) {
  size_t i = ((size_t)blockIdx.x * 256 + threadIdx.x) * 4;
  if (i >= TD) return;
  int t = (int)(i >> 11);
  int d = (int)(i & 2047);
  float4 a  = *(const float4*)(h1 + i);
  float4 p0 = *(const float4*)(pout + (size_t)(t * 2) * D_ + d);
  float4 p1 = *(const float4*)(pout + (size_t)(t * 2 + 1) * D_ + d);
  float4 s  = *(const float4*)(sho + i);
  float4 r;
  r.x = a.x + (p0.x + p1.x + s.x) * RES_MULT;
  r.y = a.y + (p0.y + p1.y + s.y) * RES_MULT;
  r.z = a.z + (p0.z + p1.z + s.z) * RES_MULT;
  r.w = a.w + (p0.w + p1.w + s.w) * RES_MULT;
  *(float4*)(out0 + i) = r;
}

// ---------------------------------------------------------------- launch
extern "C" void kernel_launch(void* const* d_in, const int* in_sizes, int n_in,
                              void* d_out, int out_size, void* d_ws, size_t ws_size,
                              hipStream_t stream) {
  const int*   pos  = (const int*)d_in[0];
  const float* hs   = (const float*)d_in[1];
  const float* ln1  = (const float*)d_in[2];
  const float* ln2  = (const float*)d_in[3];
  const float* wq   = (const float*)d_in[4];
  const float* wk   = (const float*)d_in[5];
  const float* wv   = (const float*)d_in[6];
  const float* wo   = (const float*)d_in[7];
  const float* rw   = (const float*)d_in[8];
  const float* w13  = (const float*)d_in[9];
  const float* w2   = (const float*)d_in[10];
  const float* sw13 = (const float*)d_in[11];
  const float* sw2  = (const float*)d_in[12];

  float* out = (float*)d_out;
  float* h1  = out + TD;            // residual (post-attention hidden) — 2nd tuple output

  float* w   = (float*)d_ws;
  float* xn1 = w;                   // 2M floats; later reused as act (2048x1024)
  float* qb  = xn1 + 2097152;       // 2M; later reused as shared_out (1024x2048)
  float* kb  = qb + 2097152;        // 512K
  float* vb  = kb + 524288;         // 512K
  float* at  = vb + 524288;         // 2M
  float* x2  = at + 2097152;        // 2M
  float* sa  = x2 + 2097152;        // 4M (1024x4096)
  float* po  = sa + 4194304;        // 4M (2048x2048)
  int*   tokE   = (int*)(po + 4194304);      // 2048
  float* tokW   = (float*)(tokE + 2048);     // 2048
  int*   cnt    = (int*)(tokW + 2048);       // 8
  int*   offp   = cnt + 8;                   // 8
  int*   cur    = offp + 8;                  // 8
  int*   entTok = cur + 8;                   // 2048
  float* entW   = (float*)(entTok + 2048);   // 2048
  float* act    = xn1;
  float* sho    = qb;

  rmsnorm_k<<<T_, 256, 0, stream>>>(hs, ln1, xn1);
  sgemm_qkv_k<<<dim3(24, 16), 256, 0, stream>>>(xn1, wq, wk, wv, qb, kb, vb);
  rope_k<<<(T_ * H_ * 32) / 256, 256, 0, stream>>>(qb, pos, H_);
  rope_k<<<(T_ * KV_ * 32) / 256, 256, 0, stream>>>(kb, pos, KV_);
  attn_k<<<dim3(H_, T_ / 64), 256, 0, stream>>>(qb, kb, vb, at);
  sgemm_dense_k<true><<<dim3(16, 16), 256, 0, stream>>>(at, wo, h1, hs, RES_MULT, 2048, 2048);
  rmsnorm_k<<<T_, 256, 0, stream>>>(h1, ln2, x2);
  router_k<<<T_, 256, 0, stream>>>(x2, rw, tokE, tokW);
  count_k<<<1, 256, 0, stream>>>(tokE, cnt, offp, cur);
  scatter_k<<<8, 256, 0, stream>>>(tokE, tokW, offp, cur, entTok, entW);
  gemm_dual_silu_k<true><<<dim3(16, 16, 8), 256, 0, stream>>>(
      x2, w13, 2 * I_, I_, (long)D_ * 2 * I_, act, I_, entTok, entW, cnt, offp, D_);
  gemm_w2_k<<<dim3(16, 16, 8), 256, 0, stream>>>(act, w2, po, entTok, cnt, offp);
  gemm_dual_silu_k<false><<<dim3(64, 16, 1), 256, 0, stream>>>(
      x2, sw13, 2 * SI_, SI_, 0L, sa, SI_, nullptr, nullptr, nullptr, nullptr, D_);
  sgemm_dense_k<false><<<dim3(16, 16), 256, 0, stream>>>(sa, sw2, sho, nullptr, 1.f, SI_, 2048);
  combine_k<<<(int)(TD / 1024), 256, 0, stream>>>(h1, po, sho, out);
}

// Round 2
// 926.939 us; speedup vs baseline: 2.4773x; 2.4773x over previous
//
#include <hip/hip_runtime.h>
#include <math.h>

#define T_  1024
#define D_  2048
#define H_  32
#define KV_ 8
#define HD_ 64
#define E_  8
#define I_  1024
#define SI_ 4096

constexpr float ATTN_MULT = 0.0078125f;
constexpr float RES_MULT  = 0.22f;
constexpr float EPS_      = 1e-6f;
constexpr size_t TD = (size_t)T_ * D_;

typedef float f32x4 __attribute__((ext_vector_type(4)));
typedef _Float16 f16x8 __attribute__((ext_vector_type(8)));
typedef _Float16 f16x2 __attribute__((ext_vector_type(2)));

// ---------------------------------------------------------------- RMSNorm
__global__ __launch_bounds__(256) void rmsnorm_k(const float* __restrict__ x,
                                                 const float* __restrict__ w,
                                                 float* __restrict__ o) {
  int t = blockIdx.x;
  const float* xr = x + (size_t)t * D_;
  float ss = 0.f;
  for (int d = threadIdx.x * 4; d < D_; d += 1024) {
    float4 v = *(const float4*)(xr + d);
    ss += v.x * v.x + v.y * v.y + v.z * v.z + v.w * v.w;
  }
  int lane = threadIdx.x & 63, wid = threadIdx.x >> 6;
  #pragma unroll
  for (int off = 32; off >= 1; off >>= 1) ss += __shfl_xor(ss, off);
  __shared__ float red[4];
  if (lane == 0) red[wid] = ss;
  __syncthreads();
  float tot = red[0] + red[1] + red[2] + red[3];
  float rs = rsqrtf(tot / (float)D_ + EPS_);
  float* orow = o + (size_t)t * D_;
  for (int d = threadIdx.x * 4; d < D_; d += 1024) {
    float4 v = *(const float4*)(xr + d);
    float4 ww = *(const float4*)(w + d);
    float4 r;
    r.x = v.x * rs * ww.x; r.y = v.y * rs * ww.y;
    r.z = v.z * rs * ww.z; r.w = v.w * rs * ww.w;
    *(float4*)(orow + d) = r;
  }
}

// ---------------------------------------------------------------- fp16-MFMA GEMM core
// A fp32 [?][lda] (rows gathered if GATHER); B fp32 [K][ldb] (transposed on the
// fly into LDS Bs[n][k]); C fp32. Tile 128(M) x 128(N) (plain) or
// 128 x 64gate+64up (DUAL, silu fused). 256 threads = 4 waves, each wave owns
// 64x64 (plain) / 64x32 per side (dual). mfma_f32_16x16x32_f16, fp32 accum.
// LDS pad: rows of 40 halves (80B) -> 2-way bank aliasing only (free, m136).
template<bool DUAL, bool GATHER, bool BOUND, bool SCATTER, bool RESID>
__device__ __forceinline__ void gemm_core(
    const float* __restrict__ A, int lda,
    const float* __restrict__ B, int ldb, int upOff,
    float* __restrict__ C, int ldc,
    const float* __restrict__ resid, float alpha,
    const int* __restrict__ rowIdx,   // packed t*2+slot (GATHER): A row = idx>>1
    const float* __restrict__ rowW,   // per-row weight (DUAL expert)
    const int* __restrict__ outIdx,   // out row remap (SCATTER)
    int count, int K, int m0, int n0)
{
  constexpr int NSIDE = DUAL ? 2 : 1;
  constexpr int BN    = DUAL ? 64 : 128;   // per-side col width
  constexpr int NI    = DUAL ? 2 : 4;      // n-frags per wave per side
  constexpr int NJ    = DUAL ? 4 : 8;      // staged cols per thread per side
  __shared__ _Float16 As[128][40];
  __shared__ _Float16 Bs[NSIDE][BN][40];

  int tid = threadIdx.x;
  int l = tid & 63, w = tid >> 6;
  int wr = w >> 1, wc = w & 1;
  int lr = l & 15, lkb = l >> 4;

  // A staging: thread -> (row tid>>1, 16-col group (tid&1)*16), float4 loads
  int ar = tid >> 1, acg = (tid & 1) * 16;
  int am = m0 + ar;
  if (BOUND) am = (am < count) ? am : (count - 1);
  int grow = GATHER ? (rowIdx[am] >> 1) : am;
  const float* Ap = A + (size_t)grow * lda + acg;

  // B staging: thread -> k-pair (tid>>4)*2, n = (tid&15) + 16*j  (scalar loads,
  // 16-lane groups contiguous in n -> coalesced; LDS write banks spread 2-way)
  int bkp = tid >> 4, bnl = tid & 15;
  const float* Bp0 = B + (size_t)(2 * bkp) * ldb + n0 + bnl;

  f32x4 acc[NSIDE][4][NI] = {};
  float4 apf[4];
  float  bpf[NSIDE][2][NJ];

  auto loadA = [&](int kt) {
    #pragma unroll
    for (int i = 0; i < 4; i++) apf[i] = *(const float4*)(Ap + kt + i * 4);
  };
  auto loadB = [&](int kt) {
    #pragma unroll
    for (int s = 0; s < NSIDE; s++) {
      const float* bp = Bp0 + (size_t)kt * ldb + (DUAL && s ? upOff : 0);
      #pragma unroll
      for (int j = 0; j < NJ; j++) {
        bpf[s][0][j] = bp[16 * j];
        bpf[s][1][j] = bp[ldb + 16 * j];
      }
    }
  };
  auto writeA = [&]() {
    f16x8 h0 = {(_Float16)apf[0].x, (_Float16)apf[0].y, (_Float16)apf[0].z, (_Float16)apf[0].w,
                (_Float16)apf[1].x, (_Float16)apf[1].y, (_Float16)apf[1].z, (_Float16)apf[1].w};
    f16x8 h1 = {(_Float16)apf[2].x, (_Float16)apf[2].y, (_Float16)apf[2].z, (_Float16)apf[2].w,
                (_Float16)apf[3].x, (_Float16)apf[3].y, (_Float16)apf[3].z, (_Float16)apf[3].w};
    *(f16x8*)&As[ar][acg]     = h0;
    *(f16x8*)&As[ar][acg + 8] = h1;
  };
  auto writeB = [&]() {
    #pragma unroll
    for (int s = 0; s < NSIDE; s++)
      #pragma unroll
      for (int j = 0; j < NJ; j++) {
        f16x2 h = {(_Float16)bpf[s][0][j], (_Float16)bpf[s][1][j]};
        *(f16x2*)&Bs[s][bnl + 16 * j][2 * bkp] = h;
      }
  };

  loadA(0); loadB(0);
  int nk = K / 32;
  for (int kt = 0; kt < nk; kt++) {
    __syncthreads();
    writeA(); writeB();
    if (kt + 1 < nk) { loadA((kt + 1) * 32); loadB((kt + 1) * 32); }
    __syncthreads();
    f16x8 af[4];
    #pragma unroll
    for (int mi = 0; mi < 4; mi++)
      af[mi] = *(const f16x8*)&As[wr * 64 + mi * 16 + lr][lkb * 8];
    #pragma unroll
    for (int s = 0; s < NSIDE; s++) {
      #pragma unroll
      for (int ni = 0; ni < NI; ni++) {
        f16x8 bf = *(const f16x8*)&Bs[s][wc * (BN / 2) + ni * 16 + lr][lkb * 8];
        #pragma unroll
        for (int mi = 0; mi < 4; mi++)
          acc[s][mi][ni] = __builtin_amdgcn_mfma_f32_16x16x32_f16(af[mi], bf, acc[s][mi][ni], 0, 0, 0);
      }
    }
  }

  // epilogue: C/D layout col=lane&15, row=(lane>>4)*4+r
  #pragma unroll
  for (int mi = 0; mi < 4; mi++) {
    #pragma unroll
    for (int r = 0; r < 4; r++) {
      int rl = wr * 64 + mi * 16 + lkb * 4 + r;
      if (BOUND && (m0 + rl >= count)) continue;
      size_t orow = SCATTER ? (size_t)outIdx[m0 + rl] : (size_t)(m0 + rl);
      float* Cp = C + orow * ldc;
      float wt = (DUAL && GATHER) ? rowW[m0 + rl] : 1.f;
      #pragma unroll
      for (int ni = 0; ni < NI; ni++) {
        int col = n0 + wc * (BN / 2) + ni * 16 + lr;
        if (!DUAL) {
          float v = alpha * acc[0][mi][ni][r];
          if (RESID) v += resid[(size_t)(m0 + rl) * ldc + col];
          Cp[col] = v;
        } else {
          float g = acc[0][mi][ni][r], u = acc[1][mi][ni][r];
          float sv = g / (1.f + expf(-g));
          Cp[col] = sv * u * wt;
        }
      }
    }
  }
}

// fused QKV: grid.x 0..23 -> wq (16 tiles of 128), wk (4), wv (4)
__global__ __launch_bounds__(256, 2) void hgemm_qkv(const float* __restrict__ A,
    const float* __restrict__ wq, const float* __restrict__ wk, const float* __restrict__ wv,
    float* __restrict__ qo, float* __restrict__ ko, float* __restrict__ vo) {
  int bx = blockIdx.x; const float* B; float* C; int N, n0;
  if (bx < 16)      { B = wq; C = qo; N = 2048; n0 = bx * 128; }
  else if (bx < 20) { B = wk; C = ko; N = 512;  n0 = (bx - 16) * 128; }
  else              { B = wv; C = vo; N = 512;  n0 = (bx - 20) * 128; }
  gemm_core<false, false, false, false, false>(A, 2048, B, N, 0, C, N, nullptr, 1.f,
      nullptr, nullptr, nullptr, 1 << 30, 2048, blockIdx.y * 128, n0);
}

template<bool RESID>
__global__ __launch_bounds__(256, 2) void hgemm_plain(const float* __restrict__ A, int lda,
    const float* __restrict__ B, int ldb, float* __restrict__ C, int ldc,
    const float* __restrict__ resid, float alpha, int K) {
  gemm_core<false, false, false, false, RESID>(A, lda, B, ldb, 0, C, ldc, resid, alpha,
      nullptr, nullptr, nullptr, 1 << 30, K, blockIdx.y * 128, blockIdx.x * 128);
}

__global__ __launch_bounds__(256, 2) void hgemm_dual_shared(const float* __restrict__ A,
    const float* __restrict__ B, float* __restrict__ C) {
  gemm_core<true, false, false, false, false>(A, 2048, B, 2 * SI_, SI_, C, SI_, nullptr, 1.f,
      nullptr, nullptr, nullptr, 1 << 30, 2048, blockIdx.y * 128, blockIdx.x * 64);
}

__global__ __launch_bounds__(256, 2) void hgemm_dual_exp(const float* __restrict__ A,
    const float* __restrict__ w13, float* __restrict__ act,
    const int* __restrict__ entTok, const float* __restrict__ entW,
    const int* __restrict__ cnt, const int* __restrict__ off) {
  int e = blockIdx.z, count = cnt[e], m0 = blockIdx.y * 128;
  if (m0 >= count) return;
  int goff = off[e];
  gemm_core<true, true, true, false, false>(A, 2048, w13 + (size_t)e * D_ * 2 * I_, 2 * I_, I_,
      act + (size_t)goff * I_, I_, nullptr, 1.f,
      entTok + goff, entW + goff, nullptr, count, 2048, m0, blockIdx.x * 64);
}

__global__ __launch_bounds__(256, 2) void hgemm_e2(const float* __restrict__ act,
    const float* __restrict__ w2, float* __restrict__ po,
    const int* __restrict__ entTok, const int* __restrict__ cnt, const int* __restrict__ off) {
  int e = blockIdx.z, count = cnt[e], m0 = blockIdx.y * 128;
  if (m0 >= count) return;
  int goff = off[e];
  gemm_core<false, false, true, true, false>(act + (size_t)goff * I_, I_,
      w2 + (size_t)e * I_ * D_, D_, 0, po, D_, nullptr, 1.f,
      nullptr, nullptr, entTok + goff, count, I_, m0, blockIdx.x * 128);
}

// ---------------------------------------------------------------- RoPE (in place)
__global__ __launch_bounds__(256) void rope_k(float* __restrict__ x,
                                              const int* __restrict__ pos, int nheads) {
  int id = blockIdx.x * 256 + threadIdx.x;
  int total = T_ * nheads * 32;
  if (id >= total) return;
  int j = id & 31;
  int th = id >> 5;
  int hh = th % nheads;
  int t = th / nheads;
  float inv = powf(10000.0f, -(float)(2 * j) / (float)HD_);
  float ang = (float)pos[t] * inv;
  float sn, cs;
  sincosf(ang, &sn, &cs);
  size_t base = ((size_t)t * nheads + hh) * HD_;
  float x1 = x[base + j], x2 = x[base + j + 32];
  x[base + j]      = x1 * cs - x2 * sn;
  x[base + j + 32] = x2 * cs + x1 * sn;
}

// ---------------------------------------------------------------- flash attention fp32
__global__ __launch_bounds__(256) void attn_k(const float* __restrict__ q,
                                              const float* __restrict__ kb,
                                              const float* __restrict__ vb,
                                              float* __restrict__ o) {
  int h = blockIdx.x, qt = blockIdx.y;
  __shared__ float qsT[64][68];
  __shared__ float ksT[64][68];
  __shared__ float vs[64][68];
  __shared__ float psT[64][68];
  int tid = threadIdx.x, tx = tid & 15, ty = tid >> 4;
  {
    int i = tid >> 2, dq = (tid & 3) * 16;
    const float* qp = q + (size_t)(qt * 64 + i) * (H_ * HD_) + h * HD_ + dq;
    #pragma unroll
    for (int jj = 0; jj < 16; jj += 4) {
      float4 v4 = *(const float4*)(qp + jj);
      qsT[dq + jj + 0][i] = v4.x * ATTN_MULT;
      qsT[dq + jj + 1][i] = v4.y * ATTN_MULT;
      qsT[dq + jj + 2][i] = v4.z * ATTN_MULT;
      qsT[dq + jj + 3][i] = v4.w * ATTN_MULT;
    }
  }
  float m_i[4], l_i[4], o_acc[4][4];
  #pragma unroll
  for (int ii = 0; ii < 4; ii++) {
    m_i[ii] = -1e30f; l_i[ii] = 0.f;
    #pragma unroll
    for (int dj = 0; dj < 4; dj++) o_acc[ii][dj] = 0.f;
  }
  int kvh = h >> 2;
  for (int st = 0; st <= qt; st++) {
    __syncthreads();
    {
      int s = tid >> 2, dq = (tid & 3) * 16;
      const float* kp = kb + (size_t)(st * 64 + s) * (KV_ * HD_) + kvh * HD_ + dq;
      const float* vp = vb + (size_t)(st * 64 + s) * (KV_ * HD_) + kvh * HD_ + dq;
      #pragma unroll
      for (int jj = 0; jj < 16; jj += 4) {
        float4 v4 = *(const float4*)(kp + jj);
        ksT[dq + jj + 0][s] = v4.x; ksT[dq + jj + 1][s] = v4.y;
        ksT[dq + jj + 2][s] = v4.z; ksT[dq + jj + 3][s] = v4.w;
        float4 w4 = *(const float4*)(vp + jj);
        *(float4*)&vs[s][dq + jj] = w4;
      }
    }
    __syncthreads();
    float sc[4][4] = {};
    #pragma unroll 8
    for (int d = 0; d < 64; d++) {
      float4 a = *(const float4*)&qsT[d][ty * 4];
      float4 b = *(const float4*)&ksT[d][tx * 4];
      float aa[4] = {a.x, a.y, a.z, a.w};
      float bb[4] = {b.x, b.y, b.z, b.w};
      #pragma unroll
      for (int ii = 0; ii < 4; ii++)
        #pragma unroll
        for (int sj = 0; sj < 4; sj++) sc[ii][sj] += aa[ii] * bb[sj];
    }
    if (st == qt) {
      #pragma unroll
      for (int ii = 0; ii < 4; ii++)
        #pragma unroll
        for (int sj = 0; sj < 4; sj++)
          if (tx * 4 + sj > ty * 4 + ii) sc[ii][sj] = -1e30f;
    }
    float p[4][4];
    #pragma unroll
    for (int ii = 0; ii < 4; ii++) {
      float mt = fmaxf(fmaxf(sc[ii][0], sc[ii][1]), fmaxf(sc[ii][2], sc[ii][3]));
      #pragma unroll
      for (int off = 8; off >= 1; off >>= 1) mt = fmaxf(mt, __shfl_xor(mt, off));
      float mn = fmaxf(m_i[ii], mt);
      float corr = expf(m_i[ii] - mn);
      float ssum = 0.f;
      #pragma unroll
      for (int sj = 0; sj < 4; sj++) {
        float pv = expf(sc[ii][sj] - mn);
        p[ii][sj] = pv; ssum += pv;
      }
      #pragma unroll
      for (int off = 8; off >= 1; off >>= 1) ssum += __shfl_xor(ssum, off);
      l_i[ii] = l_i[ii] * corr + ssum;
      m_i[ii] = mn;
      #pragma unroll
      for (int dj = 0; dj < 4; dj++) o_acc[ii][dj] *= corr;
    }
    #pragma unroll
    for (int sj = 0; sj < 4; sj++) {
      float4 w4 = make_float4(p[0][sj], p[1][sj], p[2][sj], p[3][sj]);
      *(float4*)&psT[tx * 4 + sj][ty * 4] = w4;
    }
    __syncthreads();
    #pragma unroll 8
    for (int s = 0; s < 64; s++) {
      float4 p4 = *(const float4*)&psT[s][ty * 4];
      float4 v4 = *(const float4*)&vs[s][tx * 4];
      float pp[4] = {p4.x, p4.y, p4.z, p4.w};
      float vv[4] = {v4.x, v4.y, v4.z, v4.w};
      #pragma unroll
      for (int ii = 0; ii < 4; ii++)
        #pragma unroll
        for (int dj = 0; dj < 4; dj++) o_acc[ii][dj] += pp[ii] * vv[dj];
    }
  }
  #pragma unroll
  for (int ii = 0; ii < 4; ii++) {
    float invl = 1.f / l_i[ii];
    int row = qt * 64 + ty * 4 + ii;
    float* op = o + (size_t)row * (H_ * HD_) + h * HD_ + tx * 4;
    #pragma unroll
    for (int dj = 0; dj < 4; dj++) op[dj] = o_acc[ii][dj] * invl;
  }
}

// ---------------------------------------------------------------- router top-2
__global__ __launch_bounds__(256) void router_k(const float* __restrict__ xn,
                                                const float* __restrict__ rw,
                                                int* __restrict__ tokE,
                                                float* __restrict__ tokW) {
  int t = blockIdx.x, tid = threadIdx.x;
  const float* xr = xn + (size_t)t * D_;
  float acc[E_] = {};
  for (int d = tid * 4; d < D_; d += 1024) {
    float4 xv = *(const float4*)(xr + d);
    #pragma unroll
    for (int e = 0; e < E_; e++) {
      float4 wv = *(const float4*)(rw + (size_t)e * D_ + d);
      acc[e] += xv.x * wv.x + xv.y * wv.y + xv.z * wv.z + xv.w * wv.w;
    }
  }
  int lane = tid & 63, wid = tid >> 6;
  #pragma unroll
  for (int e = 0; e < E_; e++)
    #pragma unroll
    for (int off = 32; off >= 1; off >>= 1) acc[e] += __shfl_xor(acc[e], off);
  __shared__ float red[E_][4];
  if (lane == 0)
    #pragma unroll
    for (int e = 0; e < E_; e++) red[e][wid] = acc[e];
  __syncthreads();
  if (tid == 0) {
    float l[E_];
    #pragma unroll
    for (int e = 0; e < E_; e++) l[e] = red[e][0] + red[e][1] + red[e][2] + red[e][3];
    int e0 = 0;
    for (int e = 1; e < E_; e++) if (l[e] > l[e0]) e0 = e;
    int e1 = (e0 == 0) ? 1 : 0;
    for (int e = 0; e < E_; e++) if (e != e0 && l[e] > l[e1]) e1 = e;
    float w0 = 1.f / (1.f + expf(l[e1] - l[e0]));
    tokE[t * 2] = e0; tokE[t * 2 + 1] = e1;
    tokW[t * 2] = w0; tokW[t * 2 + 1] = 1.f - w0;
  }
}

__global__ __launch_bounds__(256) void count_k(const int* __restrict__ tokE,
                                               int* __restrict__ cnt, int* __restrict__ off,
                                               int* __restrict__ cursor) {
  __shared__ int hc[E_];
  if (threadIdx.x < E_) hc[threadIdx.x] = 0;
  __syncthreads();
  for (int i = threadIdx.x; i < T_ * 2; i += 256) atomicAdd(&hc[tokE[i]], 1);
  __syncthreads();
  if (threadIdx.x == 0) {
    int run = 0;
    for (int e = 0; e < E_; e++) { cnt[e] = hc[e]; off[e] = run; run += hc[e]; cursor[e] = 0; }
  }
}

__global__ __launch_bounds__(256) void scatter_k(const int* __restrict__ tokE,
                                                 const float* __restrict__ tokW,
                                                 const int* __restrict__ off,
                                                 int* __restrict__ cursor,
                                                 int* __restrict__ entTok,
                                                 float* __restrict__ entW) {
  int i = blockIdx.x * 256 + threadIdx.x;
  if (i >= T_ * 2) return;
  int e = tokE[i];
  int pos = atomicAdd(&cursor[e], 1);
  entTok[off[e] + pos] = i;          // packed t*2 + slot
  entW[off[e] + pos] = tokW[i];
}

// ---------------------------------------------------------------- combine
__global__ __launch_bounds__(256) void combine_k(const float* __restrict__ h1,
                                                 const float* __restrict__ pout,
                                                 const float* __restrict__ sho,
                                                 float* __restrict__ out0) {
  size_t i = ((size_t)blockIdx.x * 256 + threadIdx.x) * 4;
  if (i >= TD) return;
  int t = (int)(i >> 11);
  int d = (int)(i & 2047);
  float4 a  = *(const float4*)(h1 + i);
  float4 p0 = *(const float4*)(pout + (size_t)(t * 2) * D_ + d);
  float4 p1 = *(const float4*)(pout + (size_t)(t * 2 + 1) * D_ + d);
  float4 s  = *(const float4*)(sho + i);
  float4 r;
  r.x = a.x + (p0.x + p1.x + s.x) * RES_MULT;
  r.y = a.y + (p0.y + p1.y + s.y) * RES_MULT;
  r.z = a.z + (p0.z + p1.z + s.z) * RES_MULT;
  r.w = a.w + (p0.w + p1.w + s.w) * RES_MULT;
  *(float4*)(out0 + i) = r;
}

// ---------------------------------------------------------------- launch
extern "C" void kernel_launch(void* const* d_in, const int* in_sizes, int n_in,
                              void* d_out, int out_size, void* d_ws, size_t ws_size,
                              hipStream_t stream) {
  const int*   pos  = (const int*)d_in[0];
  const float* hs   = (const float*)d_in[1];
  const float* ln1  = (const float*)d_in[2];
  const float* ln2  = (const float*)d_in[3];
  const float* wq   = (const float*)d_in[4];
  const float* wk   = (const float*)d_in[5];
  const float* wv   = (const float*)d_in[6];
  const float* wo   = (const float*)d_in[7];
  const float* rw   = (const float*)d_in[8];
  const float* w13  = (const float*)d_in[9];
  const float* w2   = (const float*)d_in[10];
  const float* sw13 = (const float*)d_in[11];
  const float* sw2  = (const float*)d_in[12];

  float* out = (float*)d_out;
  float* h1  = out + TD;            // residual (post-attention hidden) — 2nd tuple output

  float* w   = (float*)d_ws;
  float* xn1 = w;                   // 2M @0  (later: act 2048x1024)
  float* qb  = xn1 + 2097152;       // 2M @2M (later: sho 1024x2048)
  float* kb  = qb + 2097152;        // 512K @4M
  float* vb  = kb + 524288;         // 512K @4.5M
  float* at  = vb + 524288;         // 2M @5M
  float* x2  = at + 2097152;        // 2M @7M
  float* sa  = x2 + 2097152;        // 4M @9M (1024x4096 silu'd shared act)
  float* po  = sa + 4194304;        // 4M @13M (2048x2048 per-entry expert out)
  int*   tokE   = (int*)(po + 4194304);      // @17M
  float* tokW   = (float*)(tokE + 2048);
  int*   cnt    = (int*)(tokW + 2048);
  int*   offp   = cnt + 8;
  int*   cur    = offp + 8;
  int*   entTok = cur + 8;
  float* entW   = (float*)(entTok + 2048);
  float* act    = xn1;              // alias (xn1 dead after QKV)
  float* sho    = qb;               // alias (qb dead after attention)

  rmsnorm_k<<<T_, 256, 0, stream>>>(hs, ln1, xn1);
  hgemm_qkv<<<dim3(24, 8), 256, 0, stream>>>(xn1, wq, wk, wv, qb, kb, vb);
  rope_k<<<(T_ * H_ * 32) / 256, 256, 0, stream>>>(qb, pos, H_);
  rope_k<<<(T_ * KV_ * 32) / 256, 256, 0, stream>>>(kb, pos, KV_);
  attn_k<<<dim3(H_, T_ / 64), 256, 0, stream>>>(qb, kb, vb, at);
  hgemm_plain<true><<<dim3(16, 8), 256, 0, stream>>>(at, 2048, wo, 2048, h1, 2048, hs, RES_MULT, 2048);
  rmsnorm_k<<<T_, 256, 0, stream>>>(h1, ln2, x2);
  router_k<<<T_, 256, 0, stream>>>(x2, rw, tokE, tokW);
  count_k<<<1, 256, 0, stream>>>(tokE, cnt, offp, cur);
  scatter_k<<<8, 256, 0, stream>>>(tokE, tokW, offp, cur, entTok, entW);
  hgemm_dual_exp<<<dim3(16, 8, 8), 256, 0, stream>>>(x2, w13, act, entTok, entW, cnt, offp);
  hgemm_e2<<<dim3(16, 8, 8), 256, 0, stream>>>(act, w2, po, entTok, cnt, offp);
  hgemm_dual_shared<<<dim3(64, 8), 256, 0, stream>>>(x2, sw13, sa);
  hgemm_plain<false><<<dim3(16, 8), 256, 0, stream>>>(sa, 4096, sw2, 2048, sho, 2048, nullptr, 1.f, 4096);
  combine_k<<<(int)(TD / 1024), 256, 0, stream>>>(h1, po, sho, out);
}